// Round 1
// baseline (21.414 us; speedup 1.0000x reference)
//
#include <hip/hip_runtime.h>

// Problem constants
#define B_    16
#define T_    512
#define C_    8
#define S_    64
#define KSZ_  32
#define TOUT_ 481          // T - KSZ + 1
#define EPS_  1e-8f

// Workspace layout (floats):
//   [0,128)            xmean[b*8+c]
//   [128,256)          xrstd[b*8+c]   = 1/(std+eps)
//   [256,256+16384)    knt[s][j][k2]  (transposed normalized kernel)
//   [256+16384, +2048) kk[s][k2]      = sum_j knt^2
#define WS_KNT  256
#define WS_KK   (256 + 16384)

__device__ __forceinline__ void block_reduce2(float& a, float& b, float* sbuf) {
  #pragma unroll
  for (int m = 1; m < 64; m <<= 1) {
    a += __shfl_xor(a, m, 64);
    b += __shfl_xor(b, m, 64);
  }
  int wave = threadIdx.x >> 6;
  int lane = threadIdx.x & 63;
  if (lane == 0) { sbuf[wave] = a; sbuf[4 + wave] = b; }
  __syncthreads();
  if (threadIdx.x == 0) {
    sbuf[8] = sbuf[0] + sbuf[1] + sbuf[2] + sbuf[3];
    sbuf[9] = sbuf[4] + sbuf[5] + sbuf[6] + sbuf[7];
  }
  __syncthreads();
  a = sbuf[8];
  b = sbuf[9];
}

// Blocks 0..127: x stats per (b,c). Blocks 128..191: normalize kernel s, write
// transposed layout + per-(s,k2) squared norm.
__global__ __launch_bounds__(256) void stats_kernel(
    const float* __restrict__ x, const float* __restrict__ kern,
    float* __restrict__ ws) {
  __shared__ float sbuf[10];
  int tid = threadIdx.x;
  if (blockIdx.x < 128) {
    int bc = blockIdx.x;
    int b = bc >> 3, c = bc & 7;
    const float* xp = x + b * (T_ * C_) + c;
    float v0 = xp[tid * C_];
    float v1 = xp[(tid + 256) * C_];
    float s  = v0 + v1;
    float sq = v0 * v0 + v1 * v1;
    block_reduce2(s, sq, sbuf);
    if (tid == 0) {
      float mean = s * (1.0f / T_);
      float var  = fmaxf(sq * (1.0f / T_) - mean * mean, 0.0f);
      ws[bc]       = mean;
      ws[128 + bc] = 1.0f / (sqrtf(var) + EPS_);
    }
  } else {
    int si = blockIdx.x - 128;                 // kernel index s
    float v  = kern[si * 256 + tid];           // kern[s][k2][j], tid = k2*8+j
    float sm = v, sq = v * v;
    block_reduce2(sm, sq, sbuf);
    float mean = sm * (1.0f / 256.0f);
    float var  = fmaxf(sq * (1.0f / 256.0f) - mean * mean, 0.0f);
    float rstd = 1.0f / (sqrtf(var) + EPS_);
    float vn = (v - mean) * rstd;
    int k2 = tid >> 3, j = tid & 7;
    ws[WS_KNT + si * 256 + j * 32 + k2] = vn;  // transposed [s][j][k2]
    float vn2 = vn * vn;                       // reduce over j (8-lane groups)
    vn2 += __shfl_xor(vn2, 1, 64);
    vn2 += __shfl_xor(vn2, 2, 64);
    vn2 += __shfl_xor(vn2, 4, 64);
    if (j == 0) ws[WS_KK + si * 32 + k2] = vn2;
  }
}

// Main kernel: block = (b, t-tile of 32). thread: k2 = tid&31, tq = tid>>5,
// handles t = t0 + tq + 8r for r=0..3.
#define LXS 9   // padded row stride for lx (conflict-free p loads)
__global__ __launch_bounds__(256) void lsd_kernel(
    const float* __restrict__ x, const float* __restrict__ ws,
    float* __restrict__ out) {
  __shared__ float lk[8192];        // 32-s chunk of knt: [s][j][k2]
  __shared__ float lkk[2048];       // kk[s][k2], all 64 s
  __shared__ float lx[63 * LXS];    // 63 rows x 8 ch, stride 9

  int tid = threadIdx.x;
  int b   = blockIdx.x >> 4;
  int t0  = (blockIdx.x & 15) << 5;

  // Stage normalized x rows t0..t0+62 (channel-padded)
  for (int i = tid; i < 504; i += 256) {
    int gi = t0 * 8 + i;
    float v = (gi < T_ * C_) ? x[b * (T_ * C_) + gi] : 0.0f;
    int c = i & 7;
    float vn = (v - ws[b * 8 + c]) * ws[128 + b * 8 + c];
    lx[(i >> 3) * LXS + c] = vn;
  }
  // Stage kk (2048 floats, vectorized)
  {
    const float4* kk4 = reinterpret_cast<const float4*>(ws + WS_KK);
    float4* lkk4 = reinterpret_cast<float4*>(lkk);
    #pragma unroll
    for (int i = tid; i < 512; i += 256) lkk4[i] = kk4[i];
  }

  int k2  = tid & 31;
  int tq  = tid >> 5;           // 0..7
  int off = (k2 & 3) * 8;
  int cch = k2 >> 2;
  __syncthreads();

  // Per-thread patch vectors p[r][j] and their squared norms
  float p[4][8], pp[4], m[4];
  #pragma unroll
  for (int r = 0; r < 4; ++r) {
    int trel = tq + 8 * r;
    float acc = 0.0f;
    #pragma unroll
    for (int j = 0; j < 8; ++j) {
      float v = lx[(trel + off + j) * LXS + cch];
      p[r][j] = v;
      acc = fmaf(v, v, acc);
    }
    pp[r] = acc;
    m[r]  = 3.0e38f;
  }

  const float4* kn4 = reinterpret_cast<const float4*>(ws + WS_KNT);
  float4* lk4 = reinterpret_cast<float4*>(lk);
  for (int sc = 0; sc < 2; ++sc) {
    __syncthreads();
    #pragma unroll
    for (int i = tid; i < 2048; i += 256) lk4[i] = kn4[sc * 2048 + i];
    __syncthreads();
    #pragma unroll 4
    for (int s = 0; s < 32; ++s) {
      float kn8[8];
      #pragma unroll
      for (int j = 0; j < 8; ++j) kn8[j] = lk[s * 256 + j * 32 + k2];
      float kkv = lkk[(sc * 32 + s) * 32 + k2];
      #pragma unroll
      for (int r = 0; r < 4; ++r) {
        float dot = 0.0f;
        #pragma unroll
        for (int j = 0; j < 8; ++j) dot = fmaf(p[r][j], kn8[j], dot);
        m[r] = fminf(m[r], fmaf(-2.0f, dot, kkv));
      }
    }
  }

  #pragma unroll
  for (int r = 0; r < 4; ++r) {
    int t = t0 + tq + 8 * r;
    if (t < TOUT_) out[(b * TOUT_ + t) * 32 + k2] = pp[r] + m[r];
  }
}

extern "C" void kernel_launch(void* const* d_in, const int* in_sizes, int n_in,
                              void* d_out, int out_size, void* d_ws, size_t ws_size,
                              hipStream_t stream) {
  const float* x    = (const float*)d_in[0];
  const float* kern = (const float*)d_in[1];
  float* ws  = (float*)d_ws;
  float* out = (float*)d_out;

  stats_kernel<<<192, 256, 0, stream>>>(x, kern, ws);
  lsd_kernel<<<256, 256, 0, stream>>>(x, ws, out);
}

// Round 2
// 17.554 us; speedup vs baseline: 1.2199x; 1.2199x over previous
//
#include <hip/hip_runtime.h>

// Problem constants
#define B_    16
#define T_    512
#define C_    8
#define S_    64
#define KSZ_  32
#define TOUT_ 481          // T - KSZ + 1
#define EPS_  1e-8f
#define LXS   9            // padded row stride for lx (conflict-free p loads)

// out[b,t,k2] = min_s sum_j (xn[b, t+(k2&3)*8+j, k2>>2] - kn[s,k2,j])^2
//             = pp[t,k2] + min_s (kk[s,k2] - 2*dot)
__global__ __launch_bounds__(256) void lsd_fused(
    const float* __restrict__ x, const float* __restrict__ kern,
    float* __restrict__ out) {
  __shared__ float lk[16384];    // kn transposed+swizzled: [s][j][k2 ^ (s&15)]
  __shared__ float lkk[2048];    // kk[s][k2 ^ (s&15)]
  __shared__ float lx[63 * LXS]; // normalized x rows t0..t0+62
  __shared__ float red[64];      // x-stat cross-wave scratch
  __shared__ float cstat[16];    // cmean[8], crstd[8]

  int tid = threadIdx.x;
  int b   = blockIdx.x >> 4;
  int t0  = (blockIdx.x & 15) << 5;

  // ---------- Phase A: kernel normalization (4 threads per s) ----------
  int s  = tid >> 2;       // 0..63
  int q  = tid & 3;        // quarter of the 256 elements
  int sx = s & 15;         // XOR swizzle key
  const float4* k4 = reinterpret_cast<const float4*>(kern);
  float4 kv[16];
  #pragma unroll
  for (int u = 0; u < 16; ++u) kv[u] = k4[s * 64 + q * 16 + u];

  // issue x loads early (for stats)
  const float4* x4 = reinterpret_cast<const float4*>(x) + b * 1024;
  float4 xv[4];
  #pragma unroll
  for (int u = 0; u < 4; ++u) xv[u] = x4[tid + 256 * u];

  float ksum = 0.f, ksq = 0.f;
  #pragma unroll
  for (int u = 0; u < 16; ++u) {
    ksum += kv[u].x + kv[u].y + kv[u].z + kv[u].w;
    ksq  = fmaf(kv[u].x, kv[u].x, ksq); ksq = fmaf(kv[u].y, kv[u].y, ksq);
    ksq  = fmaf(kv[u].z, kv[u].z, ksq); ksq = fmaf(kv[u].w, kv[u].w, ksq);
  }
  ksum += __shfl_xor(ksum, 1, 64); ksq += __shfl_xor(ksq, 1, 64);
  ksum += __shfl_xor(ksum, 2, 64); ksq += __shfl_xor(ksq, 2, 64);
  float kmean = ksum * (1.0f / 256.0f);
  float kvar  = fmaxf(ksq * (1.0f / 256.0f) - kmean * kmean, 0.0f);
  float krstd = 1.0f / (sqrtf(kvar) + EPS_);

  float kks[8] = {0, 0, 0, 0, 0, 0, 0, 0};
  #pragma unroll
  for (int u = 0; u < 16; ++u) {
    float vals[4] = {kv[u].x, kv[u].y, kv[u].z, kv[u].w};
    #pragma unroll
    for (int cc = 0; cc < 4; ++cc) {
      int uu  = u * 4 + cc;            // 0..63, element within this quarter
      int k2w = q * 8 + (uu >> 3);
      int jw  = uu & 7;
      float val = (vals[cc] - kmean) * krstd;
      lk[s * 256 + jw * 32 + (k2w ^ sx)] = val;   // 2-way bank conflict (free)
      kks[uu >> 3] = fmaf(val, val, kks[uu >> 3]);
    }
  }
  #pragma unroll
  for (int c8 = 0; c8 < 8; ++c8)
    lkk[s * 32 + ((q * 8 + c8) ^ sx)] = kks[c8];

  // ---------- Phase B: x channel stats ----------
  float4 s4 = {0,0,0,0}, q4 = {0,0,0,0};
  #pragma unroll
  for (int u = 0; u < 4; ++u) {
    s4.x += xv[u].x; s4.y += xv[u].y; s4.z += xv[u].z; s4.w += xv[u].w;
    q4.x = fmaf(xv[u].x, xv[u].x, q4.x); q4.y = fmaf(xv[u].y, xv[u].y, q4.y);
    q4.z = fmaf(xv[u].z, xv[u].z, q4.z); q4.w = fmaf(xv[u].w, xv[u].w, q4.w);
  }
  #pragma unroll
  for (int m = 2; m <= 32; m <<= 1) {   // reduce within wave over same parity
    s4.x += __shfl_xor(s4.x, m, 64); s4.y += __shfl_xor(s4.y, m, 64);
    s4.z += __shfl_xor(s4.z, m, 64); s4.w += __shfl_xor(s4.w, m, 64);
    q4.x += __shfl_xor(q4.x, m, 64); q4.y += __shfl_xor(q4.y, m, 64);
    q4.z += __shfl_xor(q4.z, m, 64); q4.w += __shfl_xor(q4.w, m, 64);
  }
  int lane = tid & 63, wv = tid >> 6;
  if (lane < 2) {                       // lane = parity g (0: ch0-3, 1: ch4-7)
    int base = wv * 16 + lane * 8;
    red[base + 0] = s4.x; red[base + 1] = s4.y;
    red[base + 2] = s4.z; red[base + 3] = s4.w;
    red[base + 4] = q4.x; red[base + 5] = q4.y;
    red[base + 6] = q4.z; red[base + 7] = q4.w;
  }
  __syncthreads();
  if (tid < 8) {
    int g = tid >> 2, cp = tid & 3;
    float sm = 0.f, sq = 0.f;
    #pragma unroll
    for (int w = 0; w < 4; ++w) {
      sm += red[w * 16 + g * 8 + cp];
      sq += red[w * 16 + g * 8 + 4 + cp];
    }
    float mean = sm * (1.0f / 512.0f);
    float var  = fmaxf(sq * (1.0f / 512.0f) - mean * mean, 0.0f);
    cstat[tid]     = mean;
    cstat[8 + tid] = 1.0f / (sqrtf(var) + EPS_);
  }
  __syncthreads();

  // stage normalized rows t0..t0+62 (reads are L1-hot from the stats pass)
  for (int i = tid; i < 504; i += 256) {
    int gi = t0 * 8 + i;
    float v = (gi < T_ * C_) ? x[b * (T_ * C_) + gi] : 0.0f;
    int c = i & 7;
    lx[(i >> 3) * LXS + c] = (v - cstat[c]) * cstat[8 + c];
  }
  __syncthreads();

  // ---------- Main loop ----------
  int k2  = tid & 31;
  int tq  = tid >> 5;        // 0..7
  int off = (k2 & 3) * 8;
  int cch = k2 >> 2;

  float p[4][8], pp[4], mn[4];
  #pragma unroll
  for (int r = 0; r < 4; ++r) {
    int trel = tq + 8 * r;
    float acc = 0.0f;
    #pragma unroll
    for (int j = 0; j < 8; ++j) {
      float v = lx[(trel + off + j) * LXS + cch];
      p[r][j] = v;
      acc = fmaf(v, v, acc);
    }
    pp[r] = acc;
    mn[r] = 3.0e38f;
  }

  #pragma unroll 4
  for (int si = 0; si < 64; ++si) {
    int sw = k2 ^ (si & 15);
    int sb = si * 256 + sw;
    float kn8[8];
    #pragma unroll
    for (int j = 0; j < 8; ++j) kn8[j] = lk[sb + j * 32];
    float kkv = lkk[si * 32 + sw];
    #pragma unroll
    for (int r = 0; r < 4; ++r) {
      float dot = 0.0f;
      #pragma unroll
      for (int j = 0; j < 8; ++j) dot = fmaf(p[r][j], kn8[j], dot);
      mn[r] = fminf(mn[r], fmaf(-2.0f, dot, kkv));
    }
  }

  #pragma unroll
  for (int r = 0; r < 4; ++r) {
    int t = t0 + tq + 8 * r;
    if (t < TOUT_) out[(b * TOUT_ + t) * 32 + k2] = pp[r] + mn[r];
  }
}

extern "C" void kernel_launch(void* const* d_in, const int* in_sizes, int n_in,
                              void* d_out, int out_size, void* d_ws, size_t ws_size,
                              hipStream_t stream) {
  const float* x    = (const float*)d_in[0];
  const float* kern = (const float*)d_in[1];
  float* out = (float*)d_out;
  lsd_fused<<<256, 256, 0, stream>>>(x, kern, out);
}